// Round 1
// baseline (230.169 us; speedup 1.0000x reference)
//
#include <hip/hip_runtime.h>
#include <math.h>

#define BB 4
#define SS 2048
#define EE 1024
#define HH 64
#define BS (BB*SS)   // 8192 rows total

// ---------------------------------------------------------------------------
// Kernel A: QKV projection.  qkv[which][row][h] = sum_e x[row][e] * W_which[e][h]
// 512 blocks x 192 threads. Each block: 16 rows of x staged in LDS (64 KB),
// thread (tr,tc) computes a 4x4 micro-tile: rows tr*4..+3, cols tc*4..+3 of the
// 16 x 192 output tile (192 cols = 3 matrices x 64 head dims).
// ---------------------------------------------------------------------------
__global__ __launch_bounds__(192) void qkv_proj(const float* __restrict__ x,
                                                const float* __restrict__ Wq,
                                                const float* __restrict__ Wk,
                                                const float* __restrict__ Wv,
                                                float* __restrict__ qkv) {
  __shared__ float Xs[16 * 1024];
  const int tid = threadIdx.x;
  const int blk = blockIdx.x;

  // stage 16 rows of x (coalesced float4)
  {
    const float4* x4 = (const float4*)(x + (size_t)blk * 16 * 1024);
    float4* s4 = (float4*)Xs;
    for (int i = tid; i < 4096; i += 192) s4[i] = x4[i];
  }
  __syncthreads();

  const int tr = tid / 48;          // 0..3  (row group)
  const int tc = tid % 48;          // 0..47 (col group: col = tc*4)
  const int which = tc >> 4;        // 0=q 1=k 2=v
  const int h0 = (tc & 15) << 2;    // 0..60, step 4
  const float* __restrict__ W = (which == 0) ? Wq : ((which == 1) ? Wk : Wv);

  float acc[4][4] = {{0.f,0.f,0.f,0.f},{0.f,0.f,0.f,0.f},
                     {0.f,0.f,0.f,0.f},{0.f,0.f,0.f,0.f}};

#pragma unroll 2
  for (int e = 0; e < 1024; e += 4) {
    const float4 b0 = *(const float4*)(W + (size_t)(e + 0) * 64 + h0);
    const float4 b1 = *(const float4*)(W + (size_t)(e + 1) * 64 + h0);
    const float4 b2 = *(const float4*)(W + (size_t)(e + 2) * 64 + h0);
    const float4 b3 = *(const float4*)(W + (size_t)(e + 3) * 64 + h0);
#pragma unroll
    for (int i = 0; i < 4; ++i) {
      const float4 a = *(const float4*)(Xs + (tr * 4 + i) * 1024 + e);
      acc[i][0] += a.x * b0.x + a.y * b1.x + a.z * b2.x + a.w * b3.x;
      acc[i][1] += a.x * b0.y + a.y * b1.y + a.z * b2.y + a.w * b3.y;
      acc[i][2] += a.x * b0.z + a.y * b1.z + a.z * b2.z + a.w * b3.z;
      acc[i][3] += a.x * b0.w + a.y * b1.w + a.z * b2.w + a.w * b3.w;
    }
  }

  float* __restrict__ out = qkv + (size_t)which * (BS * 64);
#pragma unroll
  for (int i = 0; i < 4; ++i) {
    const int row = blk * 16 + tr * 4 + i;
    float4 o;
    o.x = acc[i][0]; o.y = acc[i][1]; o.z = acc[i][2]; o.w = acc[i][3];
    *(float4*)(out + (size_t)row * 64 + h0) = o;
  }
}

// ---------------------------------------------------------------------------
// Kernel B: causal flash attention, fp32.
// 2048 blocks x 256 threads. Each block owns QT=4 consecutive q rows of one
// batch. Chunked over k (KC=256): thread j computes 4 scores (one per q row)
// as a serial 64-dot (K row from global/L1, Q rows broadcast from LDS),
// block-wide online-softmax (2 reductions/chunk), then PV with thread
// (g=tid/64, lane=tid%64): lane owns output dim, group g owns 64 k-positions.
// ---------------------------------------------------------------------------
__global__ __launch_bounds__(256) void attn_fwd(const float* __restrict__ qkv,
                                                float* __restrict__ out) {
  const float* __restrict__ Q = qkv;
  const float* __restrict__ K = qkv + (size_t)BS * 64;
  const float* __restrict__ V = qkv + (size_t)2 * BS * 64;

  const int tid  = threadIdx.x;
  const int lane = tid & 63;
  const int g    = tid >> 6;
  const int blk  = blockIdx.x;            // 0..2047
  const int b    = blk >> 9;              // 512 blocks per batch
  const int q0   = (blk & 511) << 2;      // first q row of this block

  __shared__ float qs[4][64];
  __shared__ float pb[4][256];
  __shared__ float wred[4][4];            // [wave][row]

  qs[tid >> 6][tid & 63] =
      Q[((size_t)b * SS + q0 + (tid >> 6)) * 64 + (tid & 63)];
  __syncthreads();

  float accp[4] = {0.f, 0.f, 0.f, 0.f};           // partial O[r][lane], group g
  float m_r[4]  = {-1e30f, -1e30f, -1e30f, -1e30f};
  float l_r[4]  = {0.f, 0.f, 0.f, 0.f};
  const int kmax = q0 + 3;                         // widest row's causal limit

  for (int k0 = 0; k0 <= kmax; k0 += 256) {
    const int j = k0 + tid;
    float s0 = -1e30f, s1 = -1e30f, s2 = -1e30f, s3 = -1e30f;
    if (j <= kmax) {
      const float* __restrict__ Krow = K + ((size_t)b * SS + j) * 64;
      float d0 = 0.f, d1 = 0.f, d2 = 0.f, d3 = 0.f;
#pragma unroll
      for (int e = 0; e < 64; e += 4) {
        const float4 kv  = *(const float4*)(Krow + e);
        const float4 q0v = *(const float4*)(&qs[0][e]);
        const float4 q1v = *(const float4*)(&qs[1][e]);
        const float4 q2v = *(const float4*)(&qs[2][e]);
        const float4 q3v = *(const float4*)(&qs[3][e]);
        d0 += kv.x * q0v.x + kv.y * q0v.y + kv.z * q0v.z + kv.w * q0v.w;
        d1 += kv.x * q1v.x + kv.y * q1v.y + kv.z * q1v.z + kv.w * q1v.w;
        d2 += kv.x * q2v.x + kv.y * q2v.y + kv.z * q2v.z + kv.w * q2v.w;
        d3 += kv.x * q3v.x + kv.y * q3v.y + kv.z * q3v.z + kv.w * q3v.w;
      }
      const float sc = 1.0f / 32.0f;  // 1/sqrt(E), E=1024
      if (j <= q0 + 0) s0 = d0 * sc;
      if (j <= q0 + 1) s1 = d1 * sc;
      if (j <= q0 + 2) s2 = d2 * sc;
      if (j <= q0 + 3) s3 = d3 * sc;
    }

    // ---- block-reduce max over 256 threads (per row) ----
    float v0 = s0, v1 = s1, v2 = s2, v3 = s3;
#pragma unroll
    for (int off = 32; off >= 1; off >>= 1) {
      v0 = fmaxf(v0, __shfl_xor(v0, off));
      v1 = fmaxf(v1, __shfl_xor(v1, off));
      v2 = fmaxf(v2, __shfl_xor(v2, off));
      v3 = fmaxf(v3, __shfl_xor(v3, off));
    }
    if (lane == 0) { wred[g][0] = v0; wred[g][1] = v1; wred[g][2] = v2; wred[g][3] = v3; }
    __syncthreads();
    float mx[4];
#pragma unroll
    for (int r = 0; r < 4; ++r)
      mx[r] = fmaxf(fmaxf(wred[0][r], wred[1][r]), fmaxf(wred[2][r], wred[3][r]));
    __syncthreads();

    // ---- online softmax update ----
    float p0, p1, p2, p3, scale[4];
    {
      float s_arr[4] = {s0, s1, s2, s3};
      float p_arr[4];
#pragma unroll
      for (int r = 0; r < 4; ++r) {
        const float mnew = fmaxf(m_r[r], mx[r]);
        scale[r] = __expf(m_r[r] - mnew);     // 0 on first chunk (m=-1e30)
        p_arr[r] = __expf(s_arr[r] - mnew);   // 0 for masked (s=-1e30)
        m_r[r] = mnew;
      }
      p0 = p_arr[0]; p1 = p_arr[1]; p2 = p_arr[2]; p3 = p_arr[3];
    }

    // ---- block-reduce sum of p (per row) ----
    float u0 = p0, u1 = p1, u2 = p2, u3 = p3;
#pragma unroll
    for (int off = 32; off >= 1; off >>= 1) {
      u0 += __shfl_xor(u0, off);
      u1 += __shfl_xor(u1, off);
      u2 += __shfl_xor(u2, off);
      u3 += __shfl_xor(u3, off);
    }
    if (lane == 0) { wred[g][0] = u0; wred[g][1] = u1; wred[g][2] = u2; wred[g][3] = u3; }
    __syncthreads();
    float psum[4];
#pragma unroll
    for (int r = 0; r < 4; ++r)
      psum[r] = (wred[0][r] + wred[1][r]) + (wred[2][r] + wred[3][r]);
    // (wred is re-written next chunk only after another __syncthreads below)

#pragma unroll
    for (int r = 0; r < 4; ++r) l_r[r] = l_r[r] * scale[r] + psum[r];
#pragma unroll
    for (int r = 0; r < 4; ++r) accp[r] *= scale[r];

    pb[0][tid] = p0; pb[1][tid] = p1; pb[2][tid] = p2; pb[3][tid] = p3;
    __syncthreads();

    // ---- PV: accp[r] += sum over this group's 64 k-positions ----
    const int base = k0 + g * 64;
    for (int jj4 = 0; jj4 < 16; ++jj4) {
      const int j0 = base + jj4 * 4;
      if (j0 > kmax) break;                  // wave-uniform
      const float4 pr0 = *(const float4*)(&pb[0][g * 64 + jj4 * 4]);
      const float4 pr1 = *(const float4*)(&pb[1][g * 64 + jj4 * 4]);
      const float4 pr2 = *(const float4*)(&pb[2][g * 64 + jj4 * 4]);
      const float4 pr3 = *(const float4*)(&pb[3][g * 64 + jj4 * 4]);
      const int r0 = j0;
      const int r1 = min(j0 + 1, kmax);      // clamped rows have p==0
      const int r2 = min(j0 + 2, kmax);
      const int r3 = min(j0 + 3, kmax);
      const float vv0 = V[((size_t)b * SS + r0) * 64 + lane];
      const float vv1 = V[((size_t)b * SS + r1) * 64 + lane];
      const float vv2 = V[((size_t)b * SS + r2) * 64 + lane];
      const float vv3 = V[((size_t)b * SS + r3) * 64 + lane];
      accp[0] += pr0.x * vv0 + pr0.y * vv1 + pr0.z * vv2 + pr0.w * vv3;
      accp[1] += pr1.x * vv0 + pr1.y * vv1 + pr1.z * vv2 + pr1.w * vv3;
      accp[2] += pr2.x * vv0 + pr2.y * vv1 + pr2.z * vv2 + pr2.w * vv3;
      accp[3] += pr3.x * vv0 + pr3.y * vv1 + pr3.z * vv2 + pr3.w * vv3;
    }
    __syncthreads();   // protect pb/wred before next chunk
  }

  // ---- combine the 4 group-partials and write out ----
  pb[0][tid] = accp[0]; pb[1][tid] = accp[1];
  pb[2][tid] = accp[2]; pb[3][tid] = accp[3];
  __syncthreads();
  if (g == 0) {
#pragma unroll
    for (int r = 0; r < 4; ++r) {
      const float o = (pb[r][lane] + pb[r][64 + lane]) +
                      (pb[r][128 + lane] + pb[r][192 + lane]);
      out[((size_t)b * SS + q0 + r) * 64 + lane] = o / l_r[r];
    }
  }
}

extern "C" void kernel_launch(void* const* d_in, const int* in_sizes, int n_in,
                              void* d_out, int out_size, void* d_ws, size_t ws_size,
                              hipStream_t stream) {
  const float* x  = (const float*)d_in[0];
  const float* Wq = (const float*)d_in[1];
  const float* Wk = (const float*)d_in[2];
  const float* Wv = (const float*)d_in[3];
  float* outp = (float*)d_out;
  float* qkv  = (float*)d_ws;  // needs 3 * 8192 * 64 * 4 B = 6 MB of scratch

  qkv_proj<<<BS / 16, 192, 0, stream>>>(x, Wq, Wk, Wv, qkv);
  attn_fwd<<<BS / 4, 256, 0, stream>>>(qkv, outp);
}

// Round 2
// 112.573 us; speedup vs baseline: 2.0446x; 2.0446x over previous
//
#include <hip/hip_runtime.h>
#include <hip/hip_bf16.h>
#include <math.h>

#define BB 4
#define SS 2048
#define EE 1024
#define HH 64
#define BS (BB*SS)   // 8192 rows total

typedef __attribute__((ext_vector_type(8))) short bf16x8;
typedef __attribute__((ext_vector_type(4))) float f32x4;

static __device__ __forceinline__ unsigned short f2b(float f) {
  __hip_bfloat16 h = __float2bfloat16(f);
  unsigned short u;
  __builtin_memcpy(&u, &h, 2);
  return u;
}

// ---------------------------------------------------------------------------
// Kernel A: QKV projection (fp32 compute, bf16 outputs).
//   qb[b*2048+s][h]  = (x·Wq)/32  (bf16, pre-scaled so attention needs no scale)
//   kb[b*2048+s][h]  =  x·Wk      (bf16, row-major)
//   vt[b][h][s]      =  x·Wv      (bf16, TRANSPOSED so PV B-frags are contiguous)
// ---------------------------------------------------------------------------
__global__ __launch_bounds__(192) void qkv_proj(const float* __restrict__ x,
                                                const float* __restrict__ Wq,
                                                const float* __restrict__ Wk,
                                                const float* __restrict__ Wv,
                                                unsigned short* __restrict__ qb,
                                                unsigned short* __restrict__ kbuf,
                                                unsigned short* __restrict__ vt) {
  __shared__ float Xs[16 * 1024];
  const int tid = threadIdx.x;
  const int blk = blockIdx.x;

  {
    const float4* x4 = (const float4*)(x + (size_t)blk * 16 * 1024);
    float4* s4 = (float4*)Xs;
    for (int i = tid; i < 4096; i += 192) s4[i] = x4[i];
  }
  __syncthreads();

  const int tr = tid / 48;          // 0..3  (row group)
  const int tc = tid % 48;          // 0..47
  const int which = tc >> 4;        // 0=q 1=k 2=v
  const int h0 = (tc & 15) << 2;    // 0..60, step 4
  const float* __restrict__ W = (which == 0) ? Wq : ((which == 1) ? Wk : Wv);

  float acc[4][4] = {{0.f,0.f,0.f,0.f},{0.f,0.f,0.f,0.f},
                     {0.f,0.f,0.f,0.f},{0.f,0.f,0.f,0.f}};

#pragma unroll 2
  for (int e = 0; e < 1024; e += 4) {
    const float4 b0 = *(const float4*)(W + (size_t)(e + 0) * 64 + h0);
    const float4 b1 = *(const float4*)(W + (size_t)(e + 1) * 64 + h0);
    const float4 b2 = *(const float4*)(W + (size_t)(e + 2) * 64 + h0);
    const float4 b3 = *(const float4*)(W + (size_t)(e + 3) * 64 + h0);
#pragma unroll
    for (int i = 0; i < 4; ++i) {
      const float4 a = *(const float4*)(Xs + (tr * 4 + i) * 1024 + e);
      acc[i][0] += a.x * b0.x + a.y * b1.x + a.z * b2.x + a.w * b3.x;
      acc[i][1] += a.x * b0.y + a.y * b1.y + a.z * b2.y + a.w * b3.y;
      acc[i][2] += a.x * b0.z + a.y * b1.z + a.z * b2.z + a.w * b3.z;
      acc[i][3] += a.x * b0.w + a.y * b1.w + a.z * b2.w + a.w * b3.w;
    }
  }

  if (which == 0) {
#pragma unroll
    for (int i = 0; i < 4; ++i) {
      const int row = blk * 16 + tr * 4 + i;
      ushort4 o;
      o.x = f2b(acc[i][0] * 0.03125f);
      o.y = f2b(acc[i][1] * 0.03125f);
      o.z = f2b(acc[i][2] * 0.03125f);
      o.w = f2b(acc[i][3] * 0.03125f);
      *(ushort4*)(qb + (size_t)row * 64 + h0) = o;
    }
  } else if (which == 1) {
#pragma unroll
    for (int i = 0; i < 4; ++i) {
      const int row = blk * 16 + tr * 4 + i;
      ushort4 o;
      o.x = f2b(acc[i][0]); o.y = f2b(acc[i][1]);
      o.z = f2b(acc[i][2]); o.w = f2b(acc[i][3]);
      *(ushort4*)(kbuf + (size_t)row * 64 + h0) = o;
    }
  } else {
    // transposed store: vt[b][h][s], scattered 2B stores (1 MB total, L2-absorbed)
#pragma unroll
    for (int i = 0; i < 4; ++i) {
      const int row = blk * 16 + tr * 4 + i;
      const int b = row >> 11;
      const int s = row & 2047;
#pragma unroll
      for (int hh = 0; hh < 4; ++hh)
        vt[((size_t)b * 64 + h0 + hh) * 2048 + s] = f2b(acc[i][hh]);
    }
  }
}

// ---------------------------------------------------------------------------
// Kernel B: causal flash attention, bf16 MFMA, no LDS.
// 512 blocks x 64 threads (1 wave). Wave owns 16 q rows (tile qt), iterates
// KV in chunks of 64 keys.
//   S^T tile:  mfma_16x16x32(A=K-frag, B=Q-frag) -> lane holds S[q=lo][key],
//              16 keys/lane: key = kbase + j0*16 + hi*4 + r.
//   softmax:   in-lane 16-max/sum + shfl_xor(16,32). m,l scalar per lane.
//   P^T frag:  pack p to bf16 pairs, 16 shfl exchange -> direct B-operand.
//   O^T tile:  mfma_16x16x32(A=V^T-frag, B=P^T-frag) -> O[q=lo][d].
// ---------------------------------------------------------------------------
__global__ __launch_bounds__(64) void attn_mfma(const unsigned short* __restrict__ qb,
                                                const unsigned short* __restrict__ kbuf,
                                                const unsigned short* __restrict__ vt,
                                                float* __restrict__ out) {
  const int lane = threadIdx.x;
  const int lo = lane & 15, hi = lane >> 4;
  const int hi4 = hi * 4;

  const int i = blockIdx.x;        // 0..511
  const int batch = i & 3;
  const int t = i >> 2;            // 0..127
  const int qt = (t & 1) ? (127 - (t >> 1)) : (t >> 1);  // snake: balance causal load

  const unsigned short* Qb = qb   + (size_t)batch * SS * 64;
  const unsigned short* Kb = kbuf + (size_t)batch * SS * 64;
  const unsigned short* Vt = vt   + (size_t)batch * 64 * SS;

  const int q = qt * 16 + lo;      // this lane's q row

  const bf16x8 qf0 = *(const bf16x8*)(Qb + (size_t)q * 64 + hi * 8);
  const bf16x8 qf1 = *(const bf16x8*)(Qb + (size_t)q * 64 + 32 + hi * 8);

  f32x4 acc[4] = {};               // acc[j][r] = O[q=lo][d = j*16 + hi*4 + r]
  float m = -1e30f, l = 0.f;

  const int kend = qt * 16 + 16;
  for (int kbase = 0; kbase < kend; kbase += 64) {
    // ---- S^T = K · Q^T  (4 j0-frags x 2 d-chunks) ----
    f32x4 s[4];
#pragma unroll
    for (int j0 = 0; j0 < 4; ++j0) {
      const unsigned short* Krow = Kb + (size_t)(kbase + j0 * 16 + lo) * 64 + hi * 8;
      const bf16x8 ka = *(const bf16x8*)(Krow);
      const bf16x8 kb2 = *(const bf16x8*)(Krow + 32);
      f32x4 c = {};
      c = __builtin_amdgcn_mfma_f32_16x16x32_bf16(ka, qf0, c, 0, 0, 0);
      c = __builtin_amdgcn_mfma_f32_16x16x32_bf16(kb2, qf1, c, 0, 0, 0);
      s[j0] = c;
    }

    // ---- causal mask (only the final chunk can touch the diagonal) ----
    if (kbase + 64 >= kend) {
#pragma unroll
      for (int j0 = 0; j0 < 4; ++j0)
#pragma unroll
        for (int r = 0; r < 4; ++r) {
          const int key = kbase + j0 * 16 + hi4 + r;
          s[j0][r] = (key > q) ? -1e30f : s[j0][r];
        }
    }

    // ---- row max over 64 keys: in-lane 16 + cross-group xor(16,32) ----
    float mx = fmaxf(fmaxf(s[0][0], s[0][1]), fmaxf(s[0][2], s[0][3]));
    mx = fmaxf(mx, fmaxf(fmaxf(s[1][0], s[1][1]), fmaxf(s[1][2], s[1][3])));
    mx = fmaxf(mx, fmaxf(fmaxf(s[2][0], s[2][1]), fmaxf(s[2][2], s[2][3])));
    mx = fmaxf(mx, fmaxf(fmaxf(s[3][0], s[3][1]), fmaxf(s[3][2], s[3][3])));
    mx = fmaxf(mx, __shfl_xor(mx, 16));
    mx = fmaxf(mx, __shfl_xor(mx, 32));

    const float mnew = fmaxf(m, mx);
    const float scale = __expf(m - mnew);   // 0 on first chunk
    m = mnew;

    // ---- p = exp(s - m), pack to bf16 pairs, row-sum ----
    unsigned int W[4][2];
    float ps = 0.f;
#pragma unroll
    for (int j0 = 0; j0 < 4; ++j0) {
      const float p0 = __expf(s[j0][0] - mnew);
      const float p1 = __expf(s[j0][1] - mnew);
      const float p2 = __expf(s[j0][2] - mnew);
      const float p3 = __expf(s[j0][3] - mnew);
      ps += (p0 + p1) + (p2 + p3);
      W[j0][0] = (unsigned int)f2b(p0) | ((unsigned int)f2b(p1) << 16);
      W[j0][1] = (unsigned int)f2b(p2) | ((unsigned int)f2b(p3) << 16);
    }
    ps += __shfl_xor(ps, 16);
    ps += __shfl_xor(ps, 32);
    l = l * scale + ps;

#pragma unroll
    for (int j = 0; j < 4; ++j) {
      acc[j][0] *= scale; acc[j][1] *= scale;
      acc[j][2] *= scale; acc[j][3] *= scale;
    }

    // ---- P^T B-frags via register exchange + PV MFMAs ----
#pragma unroll
    for (int kc = 0; kc < 2; ++kc) {
      unsigned int w[4];
#pragma unroll
      for (int wi = 0; wi < 4; ++wi) {
        // dest lane (lo,hi) word wi holds keys kc*32 + hi*8 + {2wi, 2wi+1}
        const int src = lo + ((lane & 16) << 1) + ((wi >> 1) << 4);
        const unsigned int t0 = (unsigned int)__shfl((int)W[2 * kc + 0][wi & 1], src);
        const unsigned int t1 = (unsigned int)__shfl((int)W[2 * kc + 1][wi & 1], src);
        w[wi] = (hi < 2) ? t0 : t1;
      }
      bf16x8 pB;
      __builtin_memcpy(&pB, w, 16);
#pragma unroll
      for (int j = 0; j < 4; ++j) {
        const bf16x8 va = *(const bf16x8*)(Vt + (size_t)(j * 16 + lo) * SS +
                                           kbase + kc * 32 + hi * 8);
        acc[j] = __builtin_amdgcn_mfma_f32_16x16x32_bf16(va, pB, acc[j], 0, 0, 0);
      }
    }
  }

  // ---- epilogue: O[q][d] = acc / l ----
  const float rl = 1.0f / l;
  float* Orow = out + ((size_t)batch * SS + q) * 64;
#pragma unroll
  for (int j = 0; j < 4; ++j) {
    float4 o;
    o.x = acc[j][0] * rl; o.y = acc[j][1] * rl;
    o.z = acc[j][2] * rl; o.w = acc[j][3] * rl;
    *(float4*)(Orow + j * 16 + hi4) = o;
  }
}

extern "C" void kernel_launch(void* const* d_in, const int* in_sizes, int n_in,
                              void* d_out, int out_size, void* d_ws, size_t ws_size,
                              hipStream_t stream) {
  const float* x  = (const float*)d_in[0];
  const float* Wq = (const float*)d_in[1];
  const float* Wk = (const float*)d_in[2];
  const float* Wv = (const float*)d_in[3];
  float* outp = (float*)d_out;

  unsigned short* qb = (unsigned short*)d_ws;           // 1 MB
  unsigned short* kb = qb + (size_t)BS * 64;            // 1 MB
  unsigned short* vt = kb + (size_t)BS * 64;            // 1 MB (transposed V)

  qkv_proj<<<BS / 16, 192, 0, stream>>>(x, Wq, Wk, Wv, qb, kb, vt);
  attn_mfma<<<512, 64, 0, stream>>>(qb, kb, vt, outp);
}

// Round 3
// 68.222 us; speedup vs baseline: 3.3738x; 1.6501x over previous
//
#include <hip/hip_runtime.h>
#include <hip/hip_bf16.h>
#include <math.h>

#define BB 4
#define SS 2048
#define EE 1024
#define HH 64
#define BS (BB*SS)   // 8192 rows total

typedef __attribute__((ext_vector_type(8))) short bf16x8;
typedef __attribute__((ext_vector_type(4))) float f32x4;

static __device__ __forceinline__ unsigned int f2b(float f) {
  __hip_bfloat16 h = __float2bfloat16(f);
  unsigned short u;
  __builtin_memcpy(&u, &h, 2);
  return (unsigned int)u;
}

// ---------------------------------------------------------------------------
// Kernel 0: W transpose+convert.  wt[n][e] bf16, n = which*64 + h, e = 0..1023.
// Wq rows pre-scaled by 1/32 (the attention score scale, folded into q).
// 48 blocks (3 matrices x 16 e-tiles) x 256 threads, LDS-bounce transpose.
// ---------------------------------------------------------------------------
__global__ __launch_bounds__(256) void wt_prep(const float* __restrict__ Wq,
                                               const float* __restrict__ Wk,
                                               const float* __restrict__ Wv,
                                               unsigned short* __restrict__ wt) {
  __shared__ float tile[64 * 69];
  const int blk = blockIdx.x;
  const int w = blk >> 4;          // 0=q 1=k 2=v
  const int et = blk & 15;         // e-tile (64 rows of W)
  const int t = threadIdx.x;
  const float* __restrict__ W = (w == 0) ? Wq : ((w == 1) ? Wk : Wv);

#pragma unroll
  for (int i = 0; i < 4; ++i) {
    const int idx = t + i * 256;
    const int row = idx >> 4;      // 0..63
    const int f4 = idx & 15;
    const float4 v = *(const float4*)(W + ((size_t)(et * 64 + row)) * 64 + f4 * 4);
    tile[row * 69 + f4 * 4 + 0] = v.x;
    tile[row * 69 + f4 * 4 + 1] = v.y;
    tile[row * 69 + f4 * 4 + 2] = v.z;
    tile[row * 69 + f4 * 4 + 3] = v.w;
  }
  __syncthreads();

  const float scale = (w == 0) ? 0.03125f : 1.0f;
  const int h = t >> 2;            // 0..63
  const int eg = (t & 3) * 16;     // 16-e chunk
  unsigned int o[8];
#pragma unroll
  for (int i = 0; i < 8; ++i) {
    const float a = tile[(eg + 2 * i + 0) * 69 + h] * scale;
    const float b = tile[(eg + 2 * i + 1) * 69 + h] * scale;
    o[i] = f2b(a) | (f2b(b) << 16);
  }
  unsigned short* dst = wt + ((size_t)(w * 64 + h)) * 1024 + et * 64 + eg;
  uint4 lo4; lo4.x = o[0]; lo4.y = o[1]; lo4.z = o[2]; lo4.w = o[3];
  uint4 hi4; hi4.x = o[4]; hi4.y = o[5]; hi4.z = o[6]; hi4.w = o[7];
  *(uint4*)dst = lo4;
  *(uint4*)(dst + 8) = hi4;
}

// ---------------------------------------------------------------------------
// Kernel A: QKV projection as bf16 MFMA GEMM.  [8192x1024] x [1024x192].
// 256 blocks x 512 threads (8 waves: wm=wave>>2 picks 16 rows, wn=wave&3 picks
// 48 cols). BK=64, double-buffered LDS, XOR-swizzled (byte ^= (row&7)<<4).
// x staged fp32->bf16 in registers (T14: load early, ds_write late).
// ---------------------------------------------------------------------------
__global__ __launch_bounds__(512) void qkv_mfma(const float* __restrict__ x,
                                                const unsigned short* __restrict__ wt,
                                                unsigned short* __restrict__ qb,
                                                unsigned short* __restrict__ kbuf,
                                                unsigned short* __restrict__ vtb) {
  __shared__ char smem[57344];   // xs[2][4096] | ws[2][24576]
  const int t = threadIdx.x;
  const int blk = blockIdx.x;
  const int lane = t & 63;
  const int wv = t >> 6;
  const int wm = wv >> 2;        // 0..1
  const int wn = wv & 3;         // 0..3
  const int lo = lane & 15, hi = lane >> 4;

  // staging assignment
  const int xrow = t >> 4;       // 0..31 (16 threads/row)
  const int xf4 = t & 15;
  const int wr0 = t >> 3;        // 0..63 (rows +0/+64/+128)
  const int wc = t & 7;

  const float* __restrict__ xsrc = x + ((size_t)blk * 32 + xrow) * 1024 + xf4 * 4;
  const unsigned short* __restrict__ wsrc = wt + (size_t)wr0 * 1024 + wc * 8;

  float4 xr;
  bf16x8 wrg[3];

  f32x4 acc[3] = {};

#define LOADT(kt)                                                     \
  do {                                                                \
    xr = *(const float4*)(xsrc + (kt) * 64);                          \
    wrg[0] = *(const bf16x8*)(wsrc + (kt) * 64);                      \
    wrg[1] = *(const bf16x8*)(wsrc + 64 * 1024 + (kt) * 64);          \
    wrg[2] = *(const bf16x8*)(wsrc + 128 * 1024 + (kt) * 64);         \
  } while (0)

#define WRITET(buf)                                                          \
  do {                                                                       \
    uint2 pv;                                                                \
    pv.x = f2b(xr.x) | (f2b(xr.y) << 16);                                    \
    pv.y = f2b(xr.z) | (f2b(xr.w) << 16);                                    \
    *(uint2*)&smem[(buf) * 4096 + xrow * 128 +                               \
                   ((xf4 * 8) ^ ((xrow & 7) << 4))] = pv;                    \
    char* wb = &smem[8192 + (buf) * 24576];                                  \
    const int sw = (wc * 16) ^ ((wr0 & 7) << 4);                             \
    *(bf16x8*)&wb[(wr0 + 0) * 128 + sw] = wrg[0];                            \
    *(bf16x8*)&wb[(wr0 + 64) * 128 + sw] = wrg[1];                           \
    *(bf16x8*)&wb[(wr0 + 128) * 128 + sw] = wrg[2];                          \
  } while (0)

  LOADT(0);
  WRITET(0);
  __syncthreads();

  const int arow = wm * 16 + lo;
  const int aswz = (arow & 7) << 4;

  for (int kt = 0; kt < 16; ++kt) {
    const int cur = kt & 1;
    if (kt < 15) LOADT(kt + 1);

    const char* xb = &smem[cur * 4096];
    const char* wb = &smem[8192 + cur * 24576];
    const bf16x8 a0 = *(const bf16x8*)&xb[arow * 128 + ((hi * 16) ^ aswz)];
    const bf16x8 a1 = *(const bf16x8*)&xb[arow * 128 + ((64 + hi * 16) ^ aswz)];
#pragma unroll
    for (int nf = 0; nf < 3; ++nf) {
      const int brow = wn * 48 + nf * 16 + lo;
      const int bswz = (brow & 7) << 4;
      const bf16x8 b0 = *(const bf16x8*)&wb[brow * 128 + ((hi * 16) ^ bswz)];
      const bf16x8 b1 = *(const bf16x8*)&wb[brow * 128 + ((64 + hi * 16) ^ bswz)];
      acc[nf] = __builtin_amdgcn_mfma_f32_16x16x32_bf16(a0, b0, acc[nf], 0, 0, 0);
      acc[nf] = __builtin_amdgcn_mfma_f32_16x16x32_bf16(a1, b1, acc[nf], 0, 0, 0);
    }

    if (kt < 15) WRITET(cur ^ 1);
    __syncthreads();
  }

  // epilogue: C[m][n]: m = blk*32 + wm*16 + hi*4 + r, n = wn*48 + nf*16 + lo
  const int m0 = blk * 32 + wm * 16 + hi * 4;
#pragma unroll
  for (int nf = 0; nf < 3; ++nf) {
    const int nb = wn * 48 + nf * 16;
    const int which = nb >> 6;
    const int h = (nb & 63) + lo;
#pragma unroll
    for (int r = 0; r < 4; ++r) {
      const int row = m0 + r;
      const unsigned short v = (unsigned short)f2b(acc[nf][r]);
      if (which == 0) qb[(size_t)row * 64 + h] = v;
      else if (which == 1) kbuf[(size_t)row * 64 + h] = v;
      else vtb[((size_t)(row >> 11) * 64 + h) * 2048 + (row & 2047)] = v;
    }
  }
#undef LOADT
#undef WRITET
}

// ---------------------------------------------------------------------------
// Kernel B: causal flash attention, bf16 MFMA, no LDS (unchanged from R2).
// ---------------------------------------------------------------------------
__global__ __launch_bounds__(64) void attn_mfma(const unsigned short* __restrict__ qb,
                                                const unsigned short* __restrict__ kbuf,
                                                const unsigned short* __restrict__ vt,
                                                float* __restrict__ out) {
  const int lane = threadIdx.x;
  const int lo = lane & 15, hi = lane >> 4;
  const int hi4 = hi * 4;

  const int i = blockIdx.x;        // 0..511
  const int batch = i & 3;
  const int t = i >> 2;            // 0..127
  const int qt = (t & 1) ? (127 - (t >> 1)) : (t >> 1);  // snake

  const unsigned short* Qb = qb   + (size_t)batch * SS * 64;
  const unsigned short* Kb = kbuf + (size_t)batch * SS * 64;
  const unsigned short* Vt = vt   + (size_t)batch * 64 * SS;

  const int q = qt * 16 + lo;

  const bf16x8 qf0 = *(const bf16x8*)(Qb + (size_t)q * 64 + hi * 8);
  const bf16x8 qf1 = *(const bf16x8*)(Qb + (size_t)q * 64 + 32 + hi * 8);

  f32x4 acc[4] = {};
  float m = -1e30f, l = 0.f;

  const int kend = qt * 16 + 16;
  for (int kbase = 0; kbase < kend; kbase += 64) {
    f32x4 s[4];
#pragma unroll
    for (int j0 = 0; j0 < 4; ++j0) {
      const unsigned short* Krow = Kb + (size_t)(kbase + j0 * 16 + lo) * 64 + hi * 8;
      const bf16x8 ka = *(const bf16x8*)(Krow);
      const bf16x8 kb2 = *(const bf16x8*)(Krow + 32);
      f32x4 c = {};
      c = __builtin_amdgcn_mfma_f32_16x16x32_bf16(ka, qf0, c, 0, 0, 0);
      c = __builtin_amdgcn_mfma_f32_16x16x32_bf16(kb2, qf1, c, 0, 0, 0);
      s[j0] = c;
    }

    if (kbase + 64 >= kend) {
#pragma unroll
      for (int j0 = 0; j0 < 4; ++j0)
#pragma unroll
        for (int r = 0; r < 4; ++r) {
          const int key = kbase + j0 * 16 + hi4 + r;
          s[j0][r] = (key > q) ? -1e30f : s[j0][r];
        }
    }

    float mx = fmaxf(fmaxf(s[0][0], s[0][1]), fmaxf(s[0][2], s[0][3]));
    mx = fmaxf(mx, fmaxf(fmaxf(s[1][0], s[1][1]), fmaxf(s[1][2], s[1][3])));
    mx = fmaxf(mx, fmaxf(fmaxf(s[2][0], s[2][1]), fmaxf(s[2][2], s[2][3])));
    mx = fmaxf(mx, fmaxf(fmaxf(s[3][0], s[3][1]), fmaxf(s[3][2], s[3][3])));
    mx = fmaxf(mx, __shfl_xor(mx, 16));
    mx = fmaxf(mx, __shfl_xor(mx, 32));

    const float mnew = fmaxf(m, mx);
    const float scale = __expf(m - mnew);
    m = mnew;

    unsigned int W[4][2];
    float ps = 0.f;
#pragma unroll
    for (int j0 = 0; j0 < 4; ++j0) {
      const float p0 = __expf(s[j0][0] - mnew);
      const float p1 = __expf(s[j0][1] - mnew);
      const float p2 = __expf(s[j0][2] - mnew);
      const float p3 = __expf(s[j0][3] - mnew);
      ps += (p0 + p1) + (p2 + p3);
      W[j0][0] = f2b(p0) | (f2b(p1) << 16);
      W[j0][1] = f2b(p2) | (f2b(p3) << 16);
    }
    ps += __shfl_xor(ps, 16);
    ps += __shfl_xor(ps, 32);
    l = l * scale + ps;

#pragma unroll
    for (int j = 0; j < 4; ++j) {
      acc[j][0] *= scale; acc[j][1] *= scale;
      acc[j][2] *= scale; acc[j][3] *= scale;
    }

#pragma unroll
    for (int kc = 0; kc < 2; ++kc) {
      unsigned int w[4];
#pragma unroll
      for (int wi = 0; wi < 4; ++wi) {
        const int src = lo + ((lane & 16) << 1) + ((wi >> 1) << 4);
        const unsigned int t0 = (unsigned int)__shfl((int)W[2 * kc + 0][wi & 1], src);
        const unsigned int t1 = (unsigned int)__shfl((int)W[2 * kc + 1][wi & 1], src);
        w[wi] = (hi < 2) ? t0 : t1;
      }
      bf16x8 pB;
      __builtin_memcpy(&pB, w, 16);
#pragma unroll
      for (int j = 0; j < 4; ++j) {
        const bf16x8 va = *(const bf16x8*)(Vt + (size_t)(j * 16 + lo) * SS +
                                           kbase + kc * 32 + hi * 8);
        acc[j] = __builtin_amdgcn_mfma_f32_16x16x32_bf16(va, pB, acc[j], 0, 0, 0);
      }
    }
  }

  const float rl = 1.0f / l;
  float* Orow = out + ((size_t)batch * SS + q) * 64;
#pragma unroll
  for (int j = 0; j < 4; ++j) {
    float4 o;
    o.x = acc[j][0] * rl; o.y = acc[j][1] * rl;
    o.z = acc[j][2] * rl; o.w = acc[j][3] * rl;
    *(float4*)(Orow + j * 16 + hi4) = o;
  }
}

extern "C" void kernel_launch(void* const* d_in, const int* in_sizes, int n_in,
                              void* d_out, int out_size, void* d_ws, size_t ws_size,
                              hipStream_t stream) {
  const float* x  = (const float*)d_in[0];
  const float* Wq = (const float*)d_in[1];
  const float* Wk = (const float*)d_in[2];
  const float* Wv = (const float*)d_in[3];
  float* outp = (float*)d_out;

  unsigned short* qb = (unsigned short*)d_ws;           // 1 MB
  unsigned short* kb = qb + (size_t)BS * 64;            // 1 MB
  unsigned short* vt = kb + (size_t)BS * 64;            // 1 MB
  unsigned short* wt = vt + (size_t)BS * 64;            // 384 KB (Wt[192][1024])

  wt_prep<<<48, 256, 0, stream>>>(Wq, Wk, Wv, wt);
  qkv_mfma<<<BS / 32, 512, 0, stream>>>(x, wt, qb, kb, vt);
  attn_mfma<<<512, 64, 0, stream>>>(qb, kb, vt, outp);
}

// Round 4
// 63.649 us; speedup vs baseline: 3.6162x; 1.0719x over previous
//
#include <hip/hip_runtime.h>
#include <hip/hip_bf16.h>
#include <math.h>

#define BB 4
#define SS 2048
#define EE 1024
#define HH 64
#define BS (BB*SS)   // 8192 rows total

typedef __attribute__((ext_vector_type(8))) short bf16x8;
typedef __attribute__((ext_vector_type(4))) float f32x4;

static __device__ __forceinline__ unsigned int f2b(float f) {
  __hip_bfloat16 h = __float2bfloat16(f);
  unsigned short u;
  __builtin_memcpy(&u, &h, 2);
  return (unsigned int)u;
}

// ---------------------------------------------------------------------------
// Kernel 0: W transpose+convert.  wt[n][e] bf16, n = which*64 + h, e = 0..1023.
// Wq rows pre-scaled by 1/32 (score scale folded into q). Unchanged from R3.
// ---------------------------------------------------------------------------
__global__ __launch_bounds__(256) void wt_prep(const float* __restrict__ Wq,
                                               const float* __restrict__ Wk,
                                               const float* __restrict__ Wv,
                                               unsigned short* __restrict__ wt) {
  __shared__ float tile[64 * 69];
  const int blk = blockIdx.x;
  const int w = blk >> 4;
  const int et = blk & 15;
  const int t = threadIdx.x;
  const float* __restrict__ W = (w == 0) ? Wq : ((w == 1) ? Wk : Wv);

#pragma unroll
  for (int i = 0; i < 4; ++i) {
    const int idx = t + i * 256;
    const int row = idx >> 4;
    const int f4 = idx & 15;
    const float4 v = *(const float4*)(W + ((size_t)(et * 64 + row)) * 64 + f4 * 4);
    tile[row * 69 + f4 * 4 + 0] = v.x;
    tile[row * 69 + f4 * 4 + 1] = v.y;
    tile[row * 69 + f4 * 4 + 2] = v.z;
    tile[row * 69 + f4 * 4 + 3] = v.w;
  }
  __syncthreads();

  const float scale = (w == 0) ? 0.03125f : 1.0f;
  const int h = t >> 2;
  const int eg = (t & 3) * 16;
  unsigned int o[8];
#pragma unroll
  for (int i = 0; i < 8; ++i) {
    const float a = tile[(eg + 2 * i + 0) * 69 + h] * scale;
    const float b = tile[(eg + 2 * i + 1) * 69 + h] * scale;
    o[i] = f2b(a) | (f2b(b) << 16);
  }
  unsigned short* dst = wt + ((size_t)(w * 64 + h)) * 1024 + et * 64 + eg;
  uint4 lo4; lo4.x = o[0]; lo4.y = o[1]; lo4.z = o[2]; lo4.w = o[3];
  uint4 hi4; hi4.x = o[4]; hi4.y = o[5]; hi4.z = o[6]; hi4.w = o[7];
  *(uint4*)dst = lo4;
  *(uint4*)(dst + 8) = hi4;
}

// ---------------------------------------------------------------------------
// Kernel A: QKV projection, bf16 MFMA.  [8192x1024] x [1024x192].
// 512 blocks x 256 threads (4 waves; wave wv owns 48 output cols).  BM=16.
// W B-frags loaded L2->registers directly (no W LDS), depth-1 prefetch.
// x staged fp32->bf16 through 2x2KB swizzled LDS, depth-1 reg prefetch.
// ---------------------------------------------------------------------------
__global__ __launch_bounds__(256) void qkv_mfma(const float* __restrict__ x,
                                                const unsigned short* __restrict__ wt,
                                                unsigned short* __restrict__ qb,
                                                unsigned short* __restrict__ kbuf,
                                                unsigned short* __restrict__ vtb) {
  __shared__ char xs[2][2048];
  const int t = threadIdx.x;
  const int blk = blockIdx.x;
  const int lane = t & 63;
  const int wv = t >> 6;          // 0..3 : n-group
  const int lo = lane & 15, hi = lane >> 4;

  // x staging: 16 rows x 16 float4-loaders
  const int xrow = t >> 4;
  const int xf4 = t & 15;
  const float* __restrict__ xsrc = x + ((size_t)blk * 16 + xrow) * 1024 + xf4 * 4;
  const int xswz = xrow * 128 + ((xf4 * 8) ^ ((xrow & 7) << 4));

  // W frag pointers (global, L2-resident): frag nf -> row wv*48+nf*16+lo
  const unsigned short* __restrict__ ws0 = wt + (size_t)(wv * 48 + 0 * 16 + lo) * 1024 + hi * 8;
  const unsigned short* __restrict__ ws1 = wt + (size_t)(wv * 48 + 1 * 16 + lo) * 1024 + hi * 8;
  const unsigned short* __restrict__ ws2 = wt + (size_t)(wv * 48 + 2 * 16 + lo) * 1024 + hi * 8;

  f32x4 acc[3] = {};
  float4 xrA, xrB;
  bf16x8 wA[6], wB[6];

#define LOADX(dst, kt) dst = *(const float4*)(xsrc + (kt) * 64)
#define LOADW(dst, kt)                                        \
  do {                                                        \
    dst[0] = *(const bf16x8*)(ws0 + (kt) * 64);               \
    dst[1] = *(const bf16x8*)(ws0 + (kt) * 64 + 32);          \
    dst[2] = *(const bf16x8*)(ws1 + (kt) * 64);               \
    dst[3] = *(const bf16x8*)(ws1 + (kt) * 64 + 32);          \
    dst[4] = *(const bf16x8*)(ws2 + (kt) * 64);               \
    dst[5] = *(const bf16x8*)(ws2 + (kt) * 64 + 32);          \
  } while (0)
#define WRITEX(buf, xr)                                       \
  do {                                                        \
    uint2 pv;                                                 \
    pv.x = f2b(xr.x) | (f2b(xr.y) << 16);                     \
    pv.y = f2b(xr.z) | (f2b(xr.w) << 16);                     \
    *(uint2*)&xs[buf][xswz] = pv;                             \
  } while (0)
#define COMPUTE(buf, wr)                                                     \
  do {                                                                       \
    const char* xb = xs[buf];                                                \
    const int aswz = (lo & 7) << 4;                                          \
    const bf16x8 a0 = *(const bf16x8*)&xb[lo * 128 + ((hi * 16) ^ aswz)];    \
    const bf16x8 a1 = *(const bf16x8*)&xb[lo * 128 + ((64 + hi * 16) ^ aswz)];\
    acc[0] = __builtin_amdgcn_mfma_f32_16x16x32_bf16(a0, wr[0], acc[0], 0, 0, 0); \
    acc[0] = __builtin_amdgcn_mfma_f32_16x16x32_bf16(a1, wr[1], acc[0], 0, 0, 0); \
    acc[1] = __builtin_amdgcn_mfma_f32_16x16x32_bf16(a0, wr[2], acc[1], 0, 0, 0); \
    acc[1] = __builtin_amdgcn_mfma_f32_16x16x32_bf16(a1, wr[3], acc[1], 0, 0, 0); \
    acc[2] = __builtin_amdgcn_mfma_f32_16x16x32_bf16(a0, wr[4], acc[2], 0, 0, 0); \
    acc[2] = __builtin_amdgcn_mfma_f32_16x16x32_bf16(a1, wr[5], acc[2], 0, 0, 0); \
  } while (0)

  // prologue
  LOADX(xrA, 0);
  WRITEX(0, xrA);
  LOADW(wA, 0);
  LOADW(wB, 1);
  LOADX(xrB, 1);
  __syncthreads();

#pragma unroll
  for (int p = 0; p < 8; ++p) {
    const int ke = 2 * p;       // even step: buf0, wA
    COMPUTE(0, wA);
    if (ke < 15) WRITEX(1, xrB);
    if (ke < 14) { LOADX(xrA, ke + 2); LOADW(wA, ke + 2); }
    __syncthreads();

    const int ko = 2 * p + 1;   // odd step: buf1, wB
    COMPUTE(1, wB);
    if (ko < 15) WRITEX(0, xrA);
    if (ko < 14) { LOADX(xrB, ko + 2); LOADW(wB, ko + 2); }
    __syncthreads();
  }

  // epilogue: C[m][n]: m = blk*16 + hi*4 + r, n = wv*48 + nf*16 + lo
  const int m0 = blk * 16 + hi * 4;
#pragma unroll
  for (int nf = 0; nf < 3; ++nf) {
    const int nb = wv * 48 + nf * 16;
    const int which = nb >> 6;
    const int h = (nb & 63) + lo;
#pragma unroll
    for (int r = 0; r < 4; ++r) {
      const int row = m0 + r;
      const unsigned short v = (unsigned short)f2b(acc[nf][r]);
      if (which == 0) qb[(size_t)row * 64 + h] = v;
      else if (which == 1) kbuf[(size_t)row * 64 + h] = v;
      else vtb[((size_t)(row >> 11) * 64 + h) * 2048 + (row & 2047)] = v;
    }
  }
#undef LOADX
#undef LOADW
#undef WRITEX
#undef COMPUTE
}

// ---------------------------------------------------------------------------
// Kernel B: causal flash attention, bf16 MFMA, 8-way split-K.
// 512 blocks x 512 threads (8 waves). Wave w handles key chunks
// kbase = w*64, w*64+512, ...  Per-wave online softmax; LDS merge at end.
// ---------------------------------------------------------------------------
__global__ __launch_bounds__(512) void attn_mfma(const unsigned short* __restrict__ qb,
                                                 const unsigned short* __restrict__ kbuf,
                                                 const unsigned short* __restrict__ vt,
                                                 float* __restrict__ out) {
  __shared__ __align__(16) float sacc[8][16][64];  // 32 KB
  __shared__ float sml[2][8][16];                  // m, l

  const int t = threadIdx.x;
  const int lane = t & 63;
  const int w = t >> 6;            // 0..7
  const int lo = lane & 15, hi = lane >> 4;
  const int hi4 = hi * 4;

  const int i = blockIdx.x;        // 0..511
  const int batch = i & 3;
  const int tt = i >> 2;           // 0..127
  const int qt = (tt & 1) ? (127 - (tt >> 1)) : (tt >> 1);  // snake

  const unsigned short* Qb = qb   + (size_t)batch * SS * 64;
  const unsigned short* Kb = kbuf + (size_t)batch * SS * 64;
  const unsigned short* Vt = vt   + (size_t)batch * 64 * SS;

  const int q = qt * 16 + lo;

  const bf16x8 qf0 = *(const bf16x8*)(Qb + (size_t)q * 64 + hi * 8);
  const bf16x8 qf1 = *(const bf16x8*)(Qb + (size_t)q * 64 + 32 + hi * 8);

  f32x4 acc[4] = {};
  float m = -1e30f, l = 0.f;

  const int kend = qt * 16 + 16;
  for (int kbase = w * 64; kbase < kend; kbase += 512) {
    // ---- S^T = K · Q^T ----
    f32x4 s[4];
#pragma unroll
    for (int j0 = 0; j0 < 4; ++j0) {
      const unsigned short* Krow = Kb + (size_t)(kbase + j0 * 16 + lo) * 64 + hi * 8;
      const bf16x8 ka = *(const bf16x8*)(Krow);
      const bf16x8 kb2 = *(const bf16x8*)(Krow + 32);
      f32x4 c = {};
      c = __builtin_amdgcn_mfma_f32_16x16x32_bf16(ka, qf0, c, 0, 0, 0);
      c = __builtin_amdgcn_mfma_f32_16x16x32_bf16(kb2, qf1, c, 0, 0, 0);
      s[j0] = c;
    }

    if (kbase + 64 >= kend) {     // only the diagonal-touching chunk masks
#pragma unroll
      for (int j0 = 0; j0 < 4; ++j0)
#pragma unroll
        for (int r = 0; r < 4; ++r) {
          const int key = kbase + j0 * 16 + hi4 + r;
          s[j0][r] = (key > q) ? -1e30f : s[j0][r];
        }
    }

    float mx = fmaxf(fmaxf(s[0][0], s[0][1]), fmaxf(s[0][2], s[0][3]));
    mx = fmaxf(mx, fmaxf(fmaxf(s[1][0], s[1][1]), fmaxf(s[1][2], s[1][3])));
    mx = fmaxf(mx, fmaxf(fmaxf(s[2][0], s[2][1]), fmaxf(s[2][2], s[2][3])));
    mx = fmaxf(mx, fmaxf(fmaxf(s[3][0], s[3][1]), fmaxf(s[3][2], s[3][3])));
    mx = fmaxf(mx, __shfl_xor(mx, 16));
    mx = fmaxf(mx, __shfl_xor(mx, 32));

    const float mnew = fmaxf(m, mx);
    const float scale = __expf(m - mnew);
    m = mnew;

    unsigned int W[4][2];
    float ps = 0.f;
#pragma unroll
    for (int j0 = 0; j0 < 4; ++j0) {
      const float p0 = __expf(s[j0][0] - mnew);
      const float p1 = __expf(s[j0][1] - mnew);
      const float p2 = __expf(s[j0][2] - mnew);
      const float p3 = __expf(s[j0][3] - mnew);
      ps += (p0 + p1) + (p2 + p3);
      W[j0][0] = f2b(p0) | (f2b(p1) << 16);
      W[j0][1] = f2b(p2) | (f2b(p3) << 16);
    }
    ps += __shfl_xor(ps, 16);
    ps += __shfl_xor(ps, 32);
    l = l * scale + ps;

#pragma unroll
    for (int j = 0; j < 4; ++j) {
      acc[j][0] *= scale; acc[j][1] *= scale;
      acc[j][2] *= scale; acc[j][3] *= scale;
    }

#pragma unroll
    for (int kc = 0; kc < 2; ++kc) {
      unsigned int wreg[4];
#pragma unroll
      for (int wi = 0; wi < 4; ++wi) {
        const int src = lo + ((lane & 16) << 1) + ((wi >> 1) << 4);
        const unsigned int t0 = (unsigned int)__shfl((int)W[2 * kc + 0][wi & 1], src);
        const unsigned int t1 = (unsigned int)__shfl((int)W[2 * kc + 1][wi & 1], src);
        wreg[wi] = (hi < 2) ? t0 : t1;
      }
      bf16x8 pB;
      __builtin_memcpy(&pB, wreg, 16);
#pragma unroll
      for (int j = 0; j < 4; ++j) {
        const bf16x8 va = *(const bf16x8*)(Vt + (size_t)(j * 16 + lo) * SS +
                                           kbase + kc * 32 + hi * 8);
        acc[j] = __builtin_amdgcn_mfma_f32_16x16x32_bf16(va, pB, acc[j], 0, 0, 0);
      }
    }
  }

  // ---- publish per-wave partials ----
  if (hi == 0) { sml[0][w][lo] = m; sml[1][w][lo] = l; }
#pragma unroll
  for (int j = 0; j < 4; ++j)
    *(f32x4*)&sacc[w][lo][j * 16 + hi4] = acc[j];
  __syncthreads();

  // ---- merge 8 partials; thread -> (row, 2 dims) ----
  const int row = t >> 5;          // 0..15
  const int d0 = (t & 31) * 2;     // 0..62
  float mstar = sml[0][0][row];
#pragma unroll
  for (int ww = 1; ww < 8; ++ww) mstar = fmaxf(mstar, sml[0][ww][row]);
  float lstar = 0.f, o0 = 0.f, o1 = 0.f;
#pragma unroll
  for (int ww = 0; ww < 8; ++ww) {
    const float f = __expf(sml[0][ww][row] - mstar);
    lstar += sml[1][ww][row] * f;
    const float2 a2 = *(const float2*)&sacc[ww][row][d0];
    o0 += a2.x * f;
    o1 += a2.y * f;
  }
  const float rl = 1.0f / lstar;
  float2 o; o.x = o0 * rl; o.y = o1 * rl;
  *(float2*)(out + ((size_t)batch * SS + qt * 16 + row) * 64 + d0) = o;
}

extern "C" void kernel_launch(void* const* d_in, const int* in_sizes, int n_in,
                              void* d_out, int out_size, void* d_ws, size_t ws_size,
                              hipStream_t stream) {
  const float* x  = (const float*)d_in[0];
  const float* Wq = (const float*)d_in[1];
  const float* Wk = (const float*)d_in[2];
  const float* Wv = (const float*)d_in[3];
  float* outp = (float*)d_out;

  unsigned short* qb = (unsigned short*)d_ws;           // 1 MB
  unsigned short* kb = qb + (size_t)BS * 64;            // 1 MB
  unsigned short* vt = kb + (size_t)BS * 64;            // 1 MB
  unsigned short* wt = vt + (size_t)BS * 64;            // 384 KB

  wt_prep<<<48, 256, 0, stream>>>(Wq, Wk, Wv, wt);
  qkv_mfma<<<BS / 16, 256, 0, stream>>>(x, wt, qb, kb, vt);
  attn_mfma<<<512, 512, 0, stream>>>(qb, kb, vt, outp);
}